// Round 1
// baseline (3473.317 us; speedup 1.0000x reference)
//
#include <hip/hip_runtime.h>

// Problem constants
// B=64, T=50, ROWS=COLS=64, RES=0.03, H_FULL=W_FULL=256, C_IN=6, FC=256
// flat = 14*14*32 = 6272, d_in = 6280
// state: (64,51,6), action: (64,50,2), res: (64,50,1), env: (64,256,256)
// out: (64,51,6) float32

// ---------------- shared device helpers ----------------

// Computes window/raster parameters for the NEXT conv step from state s6[0..5].
// Layout in wsI (stride 12 per batch): [0]=crow [1]=ccol [2..4]=pr [5..7]=pc [8..10]=valid
__device__ inline void compute_params(int b, const float* s6,
                                      const float* __restrict__ res,
                                      const float* __restrict__ origin,
                                      int* __restrict__ wsI)
{
    float org0 = origin[2*b+0], org1 = origin[2*b+1];
    int ccol = (int)(s6[4] / 0.03f + org1);   // trunc toward zero == astype(int32)
    int crow = (int)(s6[5] / 0.03f + org0);
    float res0 = res[b*50];                    // res[b,0,0]
    float lo0 = org0 - (float)crow + 32.0f;
    float lo1 = org1 - (float)ccol + 32.0f;
    int* w = wsI + b*12;
    w[0] = crow; w[1] = ccol;
    #pragma unroll
    for (int p=0;p<3;p++){
        float px = s6[2*p], py = s6[2*p+1];
        int rr = (int)(py/res0 + lo0);
        int cc = (int)(px/res0 + lo1);
        int v = (rr>=0 && rr<64 && cc>=0 && cc<64) ? 1 : 0;
        w[2+p] = rr; w[5+p] = cc; w[8+p] = v;
    }
}

// ---------------- init kernel ----------------
__global__ __launch_bounds__(64)
void k_init(const float* __restrict__ state, const float* __restrict__ res,
            const float* __restrict__ origin, float* __restrict__ out,
            float* __restrict__ wsS, int* __restrict__ wsI)
{
    int b = blockIdx.x; int tid = threadIdx.x;
    __shared__ float s6[6];
    if (tid < 6){
        float v = state[b*306 + tid];   // state[b,0,:]
        s6[tid] = v;
        wsS[b*6 + tid] = v;
        out[b*306 + tid] = v;           // out[b,0,:]
    }
    __syncthreads();
    if (tid == 0) compute_params(b, s6, res, origin, wsI);
}

// ---------------- conv stack kernel ----------------
// Grid: 256 WGs, WG = (batch b = blk>>2, quarter q = blk&3) with halo split by pool2 rows.
__global__ __launch_bounds__(256)
void k_conv(const float* __restrict__ action, const float* __restrict__ env,
            const float* __restrict__ w1, const float* __restrict__ b1,
            const float* __restrict__ w2, const float* __restrict__ b2,
            const int* __restrict__ wsI, float* __restrict__ wsFlat, int st)
{
    const int blk = blockIdx.x;
    const int b = blk >> 2;
    const int q = blk & 3;
    const int tid = threadIdx.x;

    // row ranges for this quarter
    const int p2lo = (q < 2) ? q*4 : 8 + (q-2)*3;   // pool2 row start
    const int p2n  = (q < 2) ? 4 : 3;               // pool2 rows
    const int p1n  = 2*p2n + 2;                     // pool1 rows (with halo)
    const int p1lo = 2*p2lo;
    const int ilo  = 4*p2lo;                        // input row start (= conv1 row start)
    const int inn  = 2*p1n + 2;                     // input rows

    __shared__ float w1l[864];            // (3,3,6,16)
    __shared__ float w2l[4608];           // (3,3,16,32)
    __shared__ float bA[16];              // b1[o] + a0*S4[o] + a1*S5[o]
    __shared__ float b2l[32];
    __shared__ float pool1s[10*31*20];    // [row][31 cols][16 ch + 4 pad]
    __shared__ unsigned char inl[22*64];  // occupancy window slice (0/1)

    // ---- phase a: stage weights, A-term, gather window ----
    for (int i = tid; i < 864;  i += 256) w1l[i] = w1[i];
    for (int i = tid; i < 4608; i += 256) w2l[i] = w2[i];
    if (tid < 32) b2l[tid] = b2[tid];
    if (tid < 16){
        float a0 = action[b*100 + st*2 + 0];
        float a1 = action[b*100 + st*2 + 1];
        float s4 = 0.f, s5 = 0.f;
        #pragma unroll
        for (int k = 0; k < 9; k++){
            s4 += w1[(k*6 + 4)*16 + tid];
            s5 += w1[(k*6 + 5)*16 + tid];
        }
        bA[tid] = b1[tid] + a0*s4 + a1*s5;
    }
    const int* wp = wsI + b*12;
    const int crow = wp[0], ccol = wp[1];
    for (int idx = tid; idx < inn*64; idx += 256){
        int i = idx >> 6, j = idx & 63;
        int r = crow - 32 + ilo + i;
        int c = ccol - 32 + j;
        float v = (r >= 0 && r < 256 && c >= 0 && c < 256) ? env[b*65536 + (r<<8) + c] : 0.f;
        inl[idx] = (unsigned char)v;
    }
    __syncthreads();

    // ---- phase b: conv1 (1-ch + const + sparse points) fused with pool1 ----
    int pr[3], pc[3], pvld[3];
    #pragma unroll
    for (int p = 0; p < 3; p++){ pr[p] = wp[2+p]; pc[p] = wp[5+p]; pvld[p] = wp[8+p]; }

    for (int u = tid; u < p1n*31; u += 256){
        int pl = u / 31;
        int j  = u - pl*31;
        float l[4][4];
        #pragma unroll
        for (int dy = 0; dy < 4; dy++)
            #pragma unroll
            for (int dx = 0; dx < 4; dx++)
                l[dy][dx] = (float)inl[(2*pl + dy)*64 + 2*j + dx];

        float m[16];
        #pragma unroll
        for (int o = 0; o < 16; o++) m[o] = 0.f;   // relu output >= 0, so 0-init is valid for max

        #pragma unroll
        for (int dy = 0; dy < 2; dy++){
            #pragma unroll
            for (int dx = 0; dx < 2; dx++){
                int rg = 2*(p1lo + pl) + dy;     // global conv1 row
                int cg = 2*j + dx;               // global conv1 col
                bool pf[3]; int pidx[3];
                #pragma unroll
                for (int p = 0; p < 3; p++){
                    int kr = pr[p] - rg, kc = pc[p] - cg;
                    pf[p] = pvld[p] && kr >= 0 && kr < 3 && kc >= 0 && kc < 3;
                    pidx[p] = pf[p] ? ((kr*3 + kc)*6 + p)*16 : 0;
                }
                #pragma unroll
                for (int o = 0; o < 16; o++){
                    float v = bA[o];
                    #pragma unroll
                    for (int kr = 0; kr < 3; kr++)
                        #pragma unroll
                        for (int kc = 0; kc < 3; kc++)
                            v = fmaf(l[dy+kr][dx+kc], w1l[((kr*3 + kc)*6 + 3)*16 + o], v);
                    if (pf[0]) v += w1l[pidx[0] + o];
                    if (pf[1]) v += w1l[pidx[1] + o];
                    if (pf[2]) v += w1l[pidx[2] + o];
                    v = fmaxf(v, 0.f);
                    m[o] = fmaxf(m[o], v);
                }
            }
        }
        float* pd = &pool1s[(pl*31 + j)*20];
        #pragma unroll
        for (int o = 0; o < 16; o++) pd[o] = m[o];
    }
    __syncthreads();

    // ---- phase c: conv2 fused with pool2, write flat slice ----
    // unit = (pool2 row pi, col jj, o-quarter oq); 2x2 quad x 8 channels in registers
    const int units = p2n*14*4;
    for (int u = tid; u < units; u += 256){
        int pi  = u / 56;
        int rem = u - pi*56;
        int jj  = rem >> 2;
        int oq  = rem & 3;
        int o0  = oq*8;

        float acc[4][8];
        #pragma unroll
        for (int ps = 0; ps < 4; ps++)
            #pragma unroll
            for (int ow = 0; ow < 8; ow++) acc[ps][ow] = 0.f;

        #pragma unroll 1
        for (int t9 = 0; t9 < 9; t9++){
            int kr = t9 / 3, kc = t9 - 3*(t9/3);
            const float* pb = &pool1s[((2*pi + kr)*31 + (2*jj + kc))*20];
            const float* wb = &w2l[(kr*3 + kc)*16*32 + o0];
            #pragma unroll
            for (int kib = 0; kib < 4; kib++){
                float4 q00 = *(const float4*)(pb + kib*4);
                float4 q01 = *(const float4*)(pb + 20 + kib*4);
                float4 q10 = *(const float4*)(pb + 620 + kib*4);
                float4 q11 = *(const float4*)(pb + 640 + kib*4);
                float pq[4][4] = {
                    {q00.x, q00.y, q00.z, q00.w},
                    {q01.x, q01.y, q01.z, q01.w},
                    {q10.x, q10.y, q10.z, q10.w},
                    {q11.x, q11.y, q11.z, q11.w}};
                #pragma unroll
                for (int kk = 0; kk < 4; kk++){
                    float4 wlo = *(const float4*)(wb + (kib*4 + kk)*32);
                    float4 whi = *(const float4*)(wb + (kib*4 + kk)*32 + 4);
                    float wv[8] = {wlo.x, wlo.y, wlo.z, wlo.w, whi.x, whi.y, whi.z, whi.w};
                    #pragma unroll
                    for (int ps = 0; ps < 4; ps++){
                        float pvv = pq[ps][kk];
                        #pragma unroll
                        for (int ow = 0; ow < 8; ow++)
                            acc[ps][ow] = fmaf(pvv, wv[ow], acc[ps][ow]);
                    }
                }
            }
        }

        int gi = p2lo + pi;
        float* dst = wsFlat + b*6272 + (gi*14 + jj)*32 + o0;
        #pragma unroll
        for (int ow = 0; ow < 8; ow++){
            float bb = b2l[o0 + ow];
            float v0 = fmaxf(acc[0][ow] + bb, 0.f);
            float v1 = fmaxf(acc[1][ow] + bb, 0.f);
            float v2 = fmaxf(acc[2][ow] + bb, 0.f);
            float v3 = fmaxf(acc[3][ow] + bb, 0.f);
            dst[ow] = fmaxf(fmaxf(v0, v1), fmaxf(v2, v3));
        }
    }
}

// ---------------- dense0 kernel ----------------
// Grid: 256 WGs. WG = (n-chunk of 16 cols, group of 4 batches). 16-way K-split per WG.
__global__ __launch_bounds__(256)
void k_dense0(const float* __restrict__ action, const float* __restrict__ w0,
              const float* __restrict__ b0, const float* __restrict__ wsFlat,
              const float* __restrict__ wsS, float* __restrict__ wsH1, int st)
{
    const int blk = blockIdx.x;
    const int nc = blk & 15;        // 16 n-chunks of 16 columns
    const int mg = blk >> 4;        // 16 groups of 4 batches
    const int n0 = nc*16;
    const int tid = threadIdx.x;

    const int unit = tid & 15;      // (batch-in-group, n-quad)
    const int ks   = tid >> 4;      // 16-way K split over flat (392 each)
    const int bl = unit >> 2;
    const int nq = unit & 3;
    const int gb = mg*4 + bl;
    const int n  = n0 + nq*4;

    const float* fl = wsFlat + gb*6272 + ks*392;
    const float* wpp = w0 + (8 + ks*392)*256 + n;

    float ax = 0.f, ay = 0.f, az = 0.f, aw = 0.f;
    #pragma unroll 4
    for (int i = 0; i < 392; i++){
        float x = fl[i];
        float4 w4 = *(const float4*)(wpp); wpp += 256;
        ax = fmaf(x, w4.x, ax);
        ay = fmaf(x, w4.y, ay);
        az = fmaf(x, w4.z, az);
        aw = fmaf(x, w4.w, aw);
    }

    __shared__ float4 red[256];
    red[tid] = make_float4(ax, ay, az, aw);
    __syncthreads();

    if (tid < 16){
        float4 a = red[tid];
        #pragma unroll
        for (int k2 = 1; k2 < 16; k2++){
            float4 r = red[k2*16 + tid];
            a.x += r.x; a.y += r.y; a.z += r.z; a.w += r.w;
        }
        int bl2 = tid >> 2, nq2 = tid & 3;
        int gb2 = mg*4 + bl2;
        int n2  = n0 + nq2*4;
        const float* s6 = wsS + gb2*6;
        #pragma unroll
        for (int j = 0; j < 6; j++){
            float4 w4 = *(const float4*)(w0 + j*256 + n2);
            float sv = s6[j];
            a.x = fmaf(sv, w4.x, a.x); a.y = fmaf(sv, w4.y, a.y);
            a.z = fmaf(sv, w4.z, a.z); a.w = fmaf(sv, w4.w, a.w);
        }
        float a0 = action[gb2*100 + st*2 + 0];
        float a1 = action[gb2*100 + st*2 + 1];
        float4 w6 = *(const float4*)(w0 + 6*256 + n2);
        float4 w7 = *(const float4*)(w0 + 7*256 + n2);
        a.x = fmaf(a0, w6.x, a.x); a.y = fmaf(a0, w6.y, a.y);
        a.z = fmaf(a0, w6.z, a.z); a.w = fmaf(a0, w6.w, a.w);
        a.x = fmaf(a1, w7.x, a.x); a.y = fmaf(a1, w7.y, a.y);
        a.z = fmaf(a1, w7.z, a.z); a.w = fmaf(a1, w7.w, a.w);
        float4 bb = *(const float4*)(b0 + n2);
        a.x = fmaxf(a.x + bb.x, 0.f);
        a.y = fmaxf(a.y + bb.y, 0.f);
        a.z = fmaxf(a.z + bb.z, 0.f);
        a.w = fmaxf(a.w + bb.w, 0.f);
        *(float4*)(wsH1 + gb2*256 + n2) = a;
    }
}

// ---------------- tail kernel: dense1 + dense2 + state update + next params ----------------
__global__ __launch_bounds__(256)
void k_tail(const float* __restrict__ w1d, const float* __restrict__ b1d,
            const float* __restrict__ w2d, const float* __restrict__ b2d,
            const float* __restrict__ wsH1, float* __restrict__ wsS,
            int* __restrict__ wsI, const float* __restrict__ res,
            const float* __restrict__ origin, float* __restrict__ out, int st)
{
    const int b = blockIdx.x;
    const int tid = threadIdx.x;
    __shared__ float h1l[256];
    __shared__ float wred[24];
    __shared__ float snew[6];

    h1l[tid] = wsH1[b*256 + tid];
    __syncthreads();

    // dense1: out column = tid
    float acc0 = b1d[tid], acc1 = 0.f;
    const float* wcol = w1d + tid;
    #pragma unroll 4
    for (int k = 0; k < 256; k += 2){
        acc0 = fmaf(h1l[k],   wcol[k*256],       acc0);
        acc1 = fmaf(h1l[k+1], wcol[(k+1)*256],   acc1);
    }
    float h2 = fmaxf(acc0 + acc1, 0.f);

    // dense2 partials: this thread contributes h2 * W2[tid, j]
    float p[6];
    const float* w2r = w2d + tid*6;
    #pragma unroll
    for (int j = 0; j < 6; j++) p[j] = h2 * w2r[j];
    #pragma unroll
    for (int off = 32; off > 0; off >>= 1){
        #pragma unroll
        for (int j = 0; j < 6; j++) p[j] += __shfl_down(p[j], off, 64);
    }
    int lane = tid & 63, wv = tid >> 6;
    if (lane == 0){
        #pragma unroll
        for (int j = 0; j < 6; j++) wred[wv*6 + j] = p[j];
    }
    __syncthreads();

    if (tid < 6){
        float ds = wred[tid] + wred[6+tid] + wred[12+tid] + wred[18+tid] + b2d[tid];
        float sn = wsS[b*6 + tid] + ds;
        wsS[b*6 + tid] = sn;
        snew[tid] = sn;
        out[b*306 + (st+1)*6 + tid] = sn;
    }
    __syncthreads();
    if (tid == 0) compute_params(b, snew, res, origin, wsI);
}

// ---------------- launch ----------------
extern "C" void kernel_launch(void* const* d_in, const int* in_sizes, int n_in,
                              void* d_out, int out_size, void* d_ws, size_t ws_size,
                              hipStream_t stream)
{
    (void)in_sizes; (void)n_in; (void)out_size; (void)ws_size;
    const float* action = (const float*)d_in[0];
    const float* state  = (const float*)d_in[1];
    const float* res    = (const float*)d_in[2];
    const float* env    = (const float*)d_in[3];
    const float* origin = (const float*)d_in[4];
    const float* w1  = (const float*)d_in[5];
    const float* b1  = (const float*)d_in[6];
    const float* w2  = (const float*)d_in[7];
    const float* b2  = (const float*)d_in[8];
    const float* w0  = (const float*)d_in[9];
    const float* b0  = (const float*)d_in[10];
    const float* w1d = (const float*)d_in[11];
    const float* b1d = (const float*)d_in[12];
    const float* w2d = (const float*)d_in[13];
    const float* b2d = (const float*)d_in[14];
    float* out = (float*)d_out;

    // workspace layout (floats): s[384] | h1[16384] | flat[401408] | int params[768]
    float* wsF    = (float*)d_ws;
    float* wsS    = wsF;
    float* wsH1   = wsF + 384;
    float* wsFlat = wsF + 384 + 16384;
    int*   wsI    = (int*)(wsF + 384 + 16384 + 401408);

    k_init<<<dim3(64), dim3(64), 0, stream>>>(state, res, origin, out, wsS, wsI);
    for (int st = 0; st < 50; ++st){
        k_conv<<<dim3(256), dim3(256), 0, stream>>>(action, env, w1, b1, w2, b2, wsI, wsFlat, st);
        k_dense0<<<dim3(256), dim3(256), 0, stream>>>(action, w0, b0, wsFlat, wsS, wsH1, st);
        k_tail<<<dim3(64), dim3(256), 0, stream>>>(w1d, b1d, w2d, b2d, wsH1, wsS, wsI, res, origin, out, st);
    }
}

// Round 2
// 2272.166 us; speedup vs baseline: 1.5286x; 1.5286x over previous
//
#include <hip/hip_runtime.h>

// Problem constants
// B=64, T=50, ROWS=COLS=64, RES=0.03, H_FULL=W_FULL=256, C_IN=6, FC=256
// flat = 14*14*32 = 6272, d_in = 6280
// state: (64,51,6), action: (64,50,2), res: (64,50,1), env: (64,256,256)
// out: (64,51,6) float32

// ---------------- shared device helpers ----------------

// Computes window/raster parameters for the NEXT conv step from state s6[0..5].
// Layout in wsI (stride 12 per batch): [0]=crow [1]=ccol [2..4]=pr [5..7]=pc [8..10]=valid
__device__ inline void compute_params(int b, const float* s6,
                                      const float* __restrict__ res,
                                      const float* __restrict__ origin,
                                      int* __restrict__ wsI)
{
    float org0 = origin[2*b+0], org1 = origin[2*b+1];
    int ccol = (int)(s6[4] / 0.03f + org1);   // trunc toward zero == astype(int32)
    int crow = (int)(s6[5] / 0.03f + org0);
    float res0 = res[b*50];                    // res[b,0,0]
    float lo0 = org0 - (float)crow + 32.0f;
    float lo1 = org1 - (float)ccol + 32.0f;
    int* w = wsI + b*12;
    w[0] = crow; w[1] = ccol;
    #pragma unroll
    for (int p=0;p<3;p++){
        float px = s6[2*p], py = s6[2*p+1];
        int rr = (int)(py/res0 + lo0);
        int cc = (int)(px/res0 + lo1);
        int v = (rr>=0 && rr<64 && cc>=0 && cc<64) ? 1 : 0;
        w[2+p] = rr; w[5+p] = cc; w[8+p] = v;
    }
}

// ---------------- init kernel ----------------
__global__ __launch_bounds__(64)
void k_init(const float* __restrict__ state, const float* __restrict__ res,
            const float* __restrict__ origin, float* __restrict__ out,
            float* __restrict__ wsS, int* __restrict__ wsI)
{
    int b = blockIdx.x; int tid = threadIdx.x;
    __shared__ float s6[6];
    if (tid < 6){
        float v = state[b*306 + tid];   // state[b,0,:]
        s6[tid] = v;
        wsS[b*6 + tid] = v;
        out[b*306 + tid] = v;           // out[b,0,:]
    }
    __syncthreads();
    if (tid == 0) compute_params(b, s6, res, origin, wsI);
}

// ---------------- conv stack kernel ----------------
// Grid: 256 WGs, WG = (batch b = blk>>2, quarter q = blk&3) with halo split by pool2 rows.
__global__ __launch_bounds__(256)
void k_conv(const float* __restrict__ action, const float* __restrict__ env,
            const float* __restrict__ w1, const float* __restrict__ b1,
            const float* __restrict__ w2, const float* __restrict__ b2,
            const int* __restrict__ wsI, float* __restrict__ wsFlat, int st)
{
    const int blk = blockIdx.x;
    const int b = blk >> 2;
    const int q = blk & 3;
    const int tid = threadIdx.x;

    // row ranges for this quarter
    const int p2lo = (q < 2) ? q*4 : 8 + (q-2)*3;   // pool2 row start
    const int p2n  = (q < 2) ? 4 : 3;               // pool2 rows
    const int p1n  = 2*p2n + 2;                     // pool1 rows (with halo)
    const int p1lo = 2*p2lo;
    const int ilo  = 4*p2lo;                        // input row start (= conv1 row start)
    const int inn  = 2*p1n + 2;                     // input rows

    __shared__ float w1l[864];            // (3,3,6,16)
    __shared__ float w2l[4608];           // (3,3,16,32)
    __shared__ float bA[16];              // b1[o] + a0*S4[o] + a1*S5[o]
    __shared__ float b2l[32];
    __shared__ float pool1s[10*31*20];    // [row][31 cols][16 ch + 4 pad]
    __shared__ unsigned char inl[22*64];  // occupancy window slice (0/1)

    // ---- phase a: stage weights, A-term, gather window ----
    for (int i = tid; i < 864;  i += 256) w1l[i] = w1[i];
    for (int i = tid; i < 4608; i += 256) w2l[i] = w2[i];
    if (tid < 32) b2l[tid] = b2[tid];
    if (tid < 16){
        float a0 = action[b*100 + st*2 + 0];
        float a1 = action[b*100 + st*2 + 1];
        float s4 = 0.f, s5 = 0.f;
        #pragma unroll
        for (int k = 0; k < 9; k++){
            s4 += w1[(k*6 + 4)*16 + tid];
            s5 += w1[(k*6 + 5)*16 + tid];
        }
        bA[tid] = b1[tid] + a0*s4 + a1*s5;
    }
    const int* wp = wsI + b*12;
    const int crow = wp[0], ccol = wp[1];
    for (int idx = tid; idx < inn*64; idx += 256){
        int i = idx >> 6, j = idx & 63;
        int r = crow - 32 + ilo + i;
        int c = ccol - 32 + j;
        float v = (r >= 0 && r < 256 && c >= 0 && c < 256) ? env[b*65536 + (r<<8) + c] : 0.f;
        inl[idx] = (unsigned char)v;
    }
    __syncthreads();

    // ---- phase b: conv1 (1-ch + const + sparse points) fused with pool1 ----
    int pr[3], pc[3], pvld[3];
    #pragma unroll
    for (int p = 0; p < 3; p++){ pr[p] = wp[2+p]; pc[p] = wp[5+p]; pvld[p] = wp[8+p]; }

    for (int u = tid; u < p1n*31; u += 256){
        int pl = u / 31;
        int j  = u - pl*31;
        float l[4][4];
        #pragma unroll
        for (int dy = 0; dy < 4; dy++)
            #pragma unroll
            for (int dx = 0; dx < 4; dx++)
                l[dy][dx] = (float)inl[(2*pl + dy)*64 + 2*j + dx];

        float m[16];
        #pragma unroll
        for (int o = 0; o < 16; o++) m[o] = 0.f;   // relu output >= 0, so 0-init is valid for max

        #pragma unroll
        for (int dy = 0; dy < 2; dy++){
            #pragma unroll
            for (int dx = 0; dx < 2; dx++){
                int rg = 2*(p1lo + pl) + dy;     // global conv1 row
                int cg = 2*j + dx;               // global conv1 col
                bool pf[3]; int pidx[3];
                #pragma unroll
                for (int p = 0; p < 3; p++){
                    int kr = pr[p] - rg, kc = pc[p] - cg;
                    pf[p] = pvld[p] && kr >= 0 && kr < 3 && kc >= 0 && kc < 3;
                    pidx[p] = pf[p] ? ((kr*3 + kc)*6 + p)*16 : 0;
                }
                #pragma unroll
                for (int o = 0; o < 16; o++){
                    float v = bA[o];
                    #pragma unroll
                    for (int kr = 0; kr < 3; kr++)
                        #pragma unroll
                        for (int kc = 0; kc < 3; kc++)
                            v = fmaf(l[dy+kr][dx+kc], w1l[((kr*3 + kc)*6 + 3)*16 + o], v);
                    if (pf[0]) v += w1l[pidx[0] + o];
                    if (pf[1]) v += w1l[pidx[1] + o];
                    if (pf[2]) v += w1l[pidx[2] + o];
                    v = fmaxf(v, 0.f);
                    m[o] = fmaxf(m[o], v);
                }
            }
        }
        float* pd = &pool1s[(pl*31 + j)*20];
        #pragma unroll
        for (int o = 0; o < 16; o++) pd[o] = m[o];
    }
    __syncthreads();

    // ---- phase c: conv2 fused with pool2, write flat slice ----
    const int units = p2n*14*4;
    for (int u = tid; u < units; u += 256){
        int pi  = u / 56;
        int rem = u - pi*56;
        int jj  = rem >> 2;
        int oq  = rem & 3;
        int o0  = oq*8;

        float acc[4][8];
        #pragma unroll
        for (int ps = 0; ps < 4; ps++)
            #pragma unroll
            for (int ow = 0; ow < 8; ow++) acc[ps][ow] = 0.f;

        #pragma unroll 1
        for (int t9 = 0; t9 < 9; t9++){
            int kr = t9 / 3, kc = t9 - 3*(t9/3);
            const float* pb = &pool1s[((2*pi + kr)*31 + (2*jj + kc))*20];
            const float* wb = &w2l[(kr*3 + kc)*16*32 + o0];
            #pragma unroll
            for (int kib = 0; kib < 4; kib++){
                float4 q00 = *(const float4*)(pb + kib*4);
                float4 q01 = *(const float4*)(pb + 20 + kib*4);
                float4 q10 = *(const float4*)(pb + 620 + kib*4);
                float4 q11 = *(const float4*)(pb + 640 + kib*4);
                float pq[4][4] = {
                    {q00.x, q00.y, q00.z, q00.w},
                    {q01.x, q01.y, q01.z, q01.w},
                    {q10.x, q10.y, q10.z, q10.w},
                    {q11.x, q11.y, q11.z, q11.w}};
                #pragma unroll
                for (int kk = 0; kk < 4; kk++){
                    float4 wlo = *(const float4*)(wb + (kib*4 + kk)*32);
                    float4 whi = *(const float4*)(wb + (kib*4 + kk)*32 + 4);
                    float wv[8] = {wlo.x, wlo.y, wlo.z, wlo.w, whi.x, whi.y, whi.z, whi.w};
                    #pragma unroll
                    for (int ps = 0; ps < 4; ps++){
                        float pvv = pq[ps][kk];
                        #pragma unroll
                        for (int ow = 0; ow < 8; ow++)
                            acc[ps][ow] = fmaf(pvv, wv[ow], acc[ps][ow]);
                    }
                }
            }
        }

        int gi = p2lo + pi;
        float* dst = wsFlat + b*6272 + (gi*14 + jj)*32 + o0;
        #pragma unroll
        for (int ow = 0; ow < 8; ow++){
            float bb = b2l[o0 + ow];
            float v0 = fmaxf(acc[0][ow] + bb, 0.f);
            float v1 = fmaxf(acc[1][ow] + bb, 0.f);
            float v2 = fmaxf(acc[2][ow] + bb, 0.f);
            float v3 = fmaxf(acc[3][ow] + bb, 0.f);
            dst[ow] = fmaxf(fmaxf(v0, v1), fmaxf(v2, v3));
        }
    }
}

// ---------------- dense0 kernel (flat part only, K-split GEMM) ----------------
// Grid: 512 WGs = ks(32) x nc(16), XCD-swizzled. WG = 4 waves.
// Wave w handles k-range [ks*196 + w*49, +49), all 64 batches, 16 cols (n0..n0+15).
// Lane: mg = lane>>2 -> batches mg*4..+3 ; nq = lane&3 -> cols n0+nq*4..+3.
// Output: wsPart[ks][64][256] partial sums (flat contribution only).
#define XROW 51   // padded LDS row stride (bank-spread)
__global__ __launch_bounds__(256)
void k_dense0(const float* __restrict__ w0, const float* __restrict__ wsFlat,
              float* __restrict__ wsPart)
{
    const int blk = blockIdx.x;
    const int lid = (blk & 7)*64 + (blk >> 3);  // XCD-swizzle: 64 consecutive lids per XCD
    const int ks = lid >> 4;       // 0..31
    const int nc = lid & 15;       // 0..15
    const int n0 = nc*16;
    const int tid = threadIdx.x;
    const int w   = tid >> 6;
    const int lane = tid & 63;
    const int mg = lane >> 2;
    const int nq = lane & 3;

    __shared__ float smem[4*64*XROW];           // 52224 B; also reused as reduce buf
    float* myx = smem + w*(64*XROW);

    const int kbase = ks*196 + w*49;

    // stage this wave's X slice: myx[b*XROW + k] = flat[b][kbase+k], k in [0,49)
    for (int i = lane; i < 64*49; i += 64){
        int b = i / 49;
        int k = i - b*49;
        myx[b*XROW + k] = wsFlat[b*6272 + kbase + k];
    }
    __syncthreads();

    float acc[4][4];
    #pragma unroll
    for (int a = 0; a < 4; a++)
        #pragma unroll
        for (int c = 0; c < 4; c++) acc[a][c] = 0.f;

    const float* wpp = w0 + (8 + kbase)*256 + n0 + nq*4;
    const float* xp  = myx + mg*4*XROW;
    #pragma unroll 7
    for (int k = 0; k < 49; k++){
        float4 w4 = *(const float4*)(wpp); wpp += 256;
        float x0 = xp[k];
        float x1 = xp[XROW   + k];
        float x2 = xp[2*XROW + k];
        float x3 = xp[3*XROW + k];
        acc[0][0] = fmaf(x0, w4.x, acc[0][0]); acc[0][1] = fmaf(x0, w4.y, acc[0][1]);
        acc[0][2] = fmaf(x0, w4.z, acc[0][2]); acc[0][3] = fmaf(x0, w4.w, acc[0][3]);
        acc[1][0] = fmaf(x1, w4.x, acc[1][0]); acc[1][1] = fmaf(x1, w4.y, acc[1][1]);
        acc[1][2] = fmaf(x1, w4.z, acc[1][2]); acc[1][3] = fmaf(x1, w4.w, acc[1][3]);
        acc[2][0] = fmaf(x2, w4.x, acc[2][0]); acc[2][1] = fmaf(x2, w4.y, acc[2][1]);
        acc[2][2] = fmaf(x2, w4.z, acc[2][2]); acc[2][3] = fmaf(x2, w4.w, acc[2][3]);
        acc[3][0] = fmaf(x3, w4.x, acc[3][0]); acc[3][1] = fmaf(x3, w4.y, acc[3][1]);
        acc[3][2] = fmaf(x3, w4.z, acc[3][2]); acc[3][3] = fmaf(x3, w4.w, acc[3][3]);
    }
    __syncthreads();   // all waves done reading their lds_x before red overwrites

    // cross-wave reduce via LDS: red[(w*64+lane)][16], row stride 17 (bank-spread)
    float* red = smem;
    {
        float* rr = red + (w*64 + lane)*17;
        #pragma unroll
        for (int j = 0; j < 16; j++) rr[j] = acc[j>>2][j&3];
    }
    __syncthreads();

    if (tid < 64){
        float v[16];
        #pragma unroll
        for (int j = 0; j < 16; j++){
            v[j] = red[(  0 + tid)*17 + j] + red[( 64 + tid)*17 + j]
                 + red[(128 + tid)*17 + j] + red[(192 + tid)*17 + j];
        }
        int mg2 = tid >> 2, nq2 = tid & 3;
        float* dst = wsPart + ks*16384 + n0 + nq2*4;   // [ks][b][256]
        #pragma unroll
        for (int j = 0; j < 16; j++){
            int bb = mg2*4 + (j >> 2);
            dst[bb*256 + (j & 3)] = v[j];
        }
    }
}

// ---------------- tail kernel: h1 reduce + dense1 + dense2 + state update + next params ----------------
__global__ __launch_bounds__(256)
void k_tail(const float* __restrict__ action, const float* __restrict__ w0,
            const float* __restrict__ b0,
            const float* __restrict__ w1d, const float* __restrict__ b1d,
            const float* __restrict__ w2d, const float* __restrict__ b2d,
            const float* __restrict__ wsPart, float* __restrict__ wsS,
            int* __restrict__ wsI, const float* __restrict__ res,
            const float* __restrict__ origin, float* __restrict__ out, int st)
{
    const int b = blockIdx.x;
    const int tid = threadIdx.x;    // = output column n of dense0
    __shared__ float h1l[256];
    __shared__ float wred[24];
    __shared__ float snew[6];

    // ---- h1 = relu(b0 + sum_ks parts + state/action rows of W0) ----
    float acc = b0[tid];
    const float* pp = wsPart + b*256 + tid;
    #pragma unroll
    for (int ks = 0; ks < 32; ks++)
        acc += pp[ks*16384];
    #pragma unroll
    for (int j = 0; j < 6; j++)
        acc = fmaf(wsS[b*6 + j], w0[j*256 + tid], acc);
    float a0 = action[b*100 + st*2 + 0];
    float a1 = action[b*100 + st*2 + 1];
    acc = fmaf(a0, w0[6*256 + tid], acc);
    acc = fmaf(a1, w0[7*256 + tid], acc);
    h1l[tid] = fmaxf(acc, 0.f);
    __syncthreads();

    // ---- dense1: out column = tid ----
    float acc0 = b1d[tid], acc1 = 0.f;
    const float* wcol = w1d + tid;
    #pragma unroll 4
    for (int k = 0; k < 256; k += 2){
        acc0 = fmaf(h1l[k],   wcol[k*256],       acc0);
        acc1 = fmaf(h1l[k+1], wcol[(k+1)*256],   acc1);
    }
    float h2 = fmaxf(acc0 + acc1, 0.f);

    // ---- dense2 partials ----
    float p[6];
    const float* w2r = w2d + tid*6;
    #pragma unroll
    for (int j = 0; j < 6; j++) p[j] = h2 * w2r[j];
    #pragma unroll
    for (int off = 32; off > 0; off >>= 1){
        #pragma unroll
        for (int j = 0; j < 6; j++) p[j] += __shfl_down(p[j], off, 64);
    }
    int lane = tid & 63, wv = tid >> 6;
    if (lane == 0){
        #pragma unroll
        for (int j = 0; j < 6; j++) wred[wv*6 + j] = p[j];
    }
    __syncthreads();

    if (tid < 6){
        float ds = wred[tid] + wred[6+tid] + wred[12+tid] + wred[18+tid] + b2d[tid];
        float sn = wsS[b*6 + tid] + ds;
        wsS[b*6 + tid] = sn;
        snew[tid] = sn;
        out[b*306 + (st+1)*6 + tid] = sn;
    }
    __syncthreads();
    if (tid == 0) compute_params(b, snew, res, origin, wsI);
}

// ---------------- launch ----------------
extern "C" void kernel_launch(void* const* d_in, const int* in_sizes, int n_in,
                              void* d_out, int out_size, void* d_ws, size_t ws_size,
                              hipStream_t stream)
{
    (void)in_sizes; (void)n_in; (void)out_size; (void)ws_size;
    const float* action = (const float*)d_in[0];
    const float* state  = (const float*)d_in[1];
    const float* res    = (const float*)d_in[2];
    const float* env    = (const float*)d_in[3];
    const float* origin = (const float*)d_in[4];
    const float* w1  = (const float*)d_in[5];
    const float* b1  = (const float*)d_in[6];
    const float* w2  = (const float*)d_in[7];
    const float* b2  = (const float*)d_in[8];
    const float* w0  = (const float*)d_in[9];
    const float* b0  = (const float*)d_in[10];
    const float* w1d = (const float*)d_in[11];
    const float* b1d = (const float*)d_in[12];
    const float* w2d = (const float*)d_in[13];
    const float* b2d = (const float*)d_in[14];
    float* out = (float*)d_out;

    // workspace layout (floats): s[384] | flat[401408] | part[524288] | int params[768]
    float* wsF    = (float*)d_ws;
    float* wsS    = wsF;
    float* wsFlat = wsF + 384;
    float* wsPart = wsF + 384 + 401408;
    int*   wsI    = (int*)(wsF + 384 + 401408 + 524288);

    k_init<<<dim3(64), dim3(64), 0, stream>>>(state, res, origin, out, wsS, wsI);
    for (int st = 0; st < 50; ++st){
        k_conv<<<dim3(256), dim3(256), 0, stream>>>(action, env, w1, b1, w2, b2, wsI, wsFlat, st);
        k_dense0<<<dim3(512), dim3(256), 0, stream>>>(w0, wsFlat, wsPart);
        k_tail<<<dim3(64), dim3(256), 0, stream>>>(action, w0, b0, w1d, b1d, w2d, b2d,
                                                   wsPart, wsS, wsI, res, origin, out, st);
    }
}